// Round 9
// baseline (141.839 us; speedup 1.0000x reference)
//
#include <hip/hip_runtime.h>
#include <hip/hip_bf16.h>
#include <math.h>

// AttentionDecoder — Bahdanau attention + 1-step LSTM + out proj.
// SEQ=4096, H=2048, NF=512. All f32 in/out.
//
// R9: R6 build (best passing, 108.0us) with ONE change: energy GEMM BK 64->128.
// We're grid-limited at 2 blocks/CU (512 blocks), so the m132 occupancy
// penalty for BK=128 doesn't apply — barrier count halves for free.
// Swizzle: 16-slot XOR (slot ^= row&15 over 256B rows), pre-swizzled global
// source (linear LDS dest), matching XOR on ds_read side.

#define HIDDEN 2048
#define SEQL   4096
#define NFEAT  512

typedef __attribute__((ext_vector_type(8))) short frag_t;   // 8 bf16
typedef __attribute__((ext_vector_type(8))) unsigned short u16x8;
typedef __attribute__((ext_vector_type(4))) float f32x4;

__device__ __forceinline__ unsigned short f2bf(float f) {
    union { float f; unsigned int u; } c; c.f = f;
    unsigned int r = c.u + 0x7fffu + ((c.u >> 16) & 1u);   // RNE
    return (unsigned short)(r >> 16);
}

__device__ __forceinline__ float bf2f(unsigned short u) {
    union { unsigned int u; float f; } c; c.u = (unsigned int)u << 16;
    return c.f;
}

__device__ __forceinline__ float wave_sum(float s) {
    #pragma unroll
    for (int off = 32; off; off >>= 1) s += __shfl_down(s, off);
    return s;
}

__device__ __forceinline__ float dot4(float4 a, float4 b) {
    return a.x*b.x + a.y*b.y + a.z*b.z + a.w*b.w;
}

__device__ __forceinline__ void gload16(const unsigned short* g, unsigned short* l) {
    __builtin_amdgcn_global_load_lds(
        (const __attribute__((address_space(1))) unsigned int*)g,
        (__attribute__((address_space(3))) unsigned int*)l, 16, 0, 0);
}

// ---------------------------------------------------------------------------
// K_A: blocks 0..4095   : enc f32->bf16
//      blocks 4096..6143: Wattn[:,2048:] f32->bf16
//      blocks 6144..6655: h_pre gemv (4 rows/block, one per wave)
//      blocks 6656..8703: gates gemv (4 rows/block):
//                         gates[j] = b_ih+b_hh + Wih[j,0:512]@x + Whh[j]@h0
__global__ __launch_bounds__(256)
void k_conv_hpre_gates(const float* __restrict__ enc, const float* __restrict__ Wattn,
                       const float* __restrict__ b_attn, const float* __restrict__ h0,
                       const float* __restrict__ Wih,  const float* __restrict__ Whh,
                       const float* __restrict__ b_ih, const float* __restrict__ b_hh,
                       const float* __restrict__ x,
                       unsigned short* __restrict__ encbf, unsigned short* __restrict__ wbf,
                       float* __restrict__ h_pre, float* __restrict__ gates)
{
    const int b = blockIdx.x;
    if (b < 6144) {
        const float* src;
        unsigned short* dst;
        if (b < 4096) {
            src = enc + (size_t)b * 2048;
            dst = encbf + (size_t)b * 2048;
        } else {
            const int r = b - 4096;
            src = Wattn + (size_t)r * 4096 + 2048;
            dst = wbf + (size_t)r * 2048;
        }
        const int t = threadIdx.x;
        float4 a = *reinterpret_cast<const float4*>(src + t * 8);
        float4 c = *reinterpret_cast<const float4*>(src + t * 8 + 4);
        u16x8 o;
        o[0] = f2bf(a.x); o[1] = f2bf(a.y); o[2] = f2bf(a.z); o[3] = f2bf(a.w);
        o[4] = f2bf(c.x); o[5] = f2bf(c.y); o[6] = f2bf(c.z); o[7] = f2bf(c.w);
        *reinterpret_cast<u16x8*>(dst + t * 8) = o;
    } else if (b < 6656) {
        const int gw = (b - 6144) * 4 + (threadIdx.x >> 6);   // row 0..2047
        const int lane = threadIdx.x & 63;
        const float* Wr = Wattn + (size_t)gw * 4096;
        float s = 0.f;
        #pragma unroll
        for (int i = 0; i < 8; i++) {
            int c = i * 256 + lane * 4;
            float4 wv = *reinterpret_cast<const float4*>(Wr + c);
            float4 hv = *reinterpret_cast<const float4*>(h0 + c);
            s += dot4(wv, hv);
        }
        s = wave_sum(s);
        if (lane == 0) h_pre[gw] = s + b_attn[gw];
    } else {
        const int j = (b - 6656) * 4 + (threadIdx.x >> 6);    // row 0..8191
        const int lane = threadIdx.x & 63;
        const float* W1 = Wih + (size_t)j * 2560;             // x part (cols 0..511)
        const float* W2 = Whh + (size_t)j * 2048;
        float s = 0.f;
        #pragma unroll
        for (int i = 0; i < 2; i++) {
            int c = i * 256 + lane * 4;
            float4 wv = *reinterpret_cast<const float4*>(W1 + c);
            float4 xv = *reinterpret_cast<const float4*>(x + c);
            s += dot4(wv, xv);
        }
        #pragma unroll
        for (int i = 0; i < 8; i++) {
            int c = i * 256 + lane * 4;
            float4 wv = *reinterpret_cast<const float4*>(W2 + c);
            float4 hv = *reinterpret_cast<const float4*>(h0 + c);
            s += dot4(wv, hv);
        }
        s = wave_sum(s);
        if (lane == 0) gates[j] = s + b_ih[j] + b_hh[j];
    }
}

// ---------------------------------------------------------------------------
// K_B: fused energy GEMM + tanh + v-dot reduction (bf16 inputs).
// C[s,h] = sum_k encbf[s,k] * wbf[h,k]    (NT, MFMA 16x16x32, f32 acc)
// pscore[hb][s] = sum_{h in tile} tanh(C[s,h] + h_pre[h]) * v[h]
// 128x128 tile, BK=128 (16 K-steps, 2 barriers each), 4 waves 2x2.
// LDS rows are 256B; swizzle: 16B-slot ^= (row&15), staged via pre-swizzled
// per-lane global source (LDS dest linear per global_load_lds rules).
__global__ __launch_bounds__(256)
void k_energy2(const unsigned short* __restrict__ encbf,
               const unsigned short* __restrict__ wbf,
               const float* __restrict__ h_pre, const float* __restrict__ v_attn,
               float* __restrict__ pscore)
{
    __shared__ __align__(16) unsigned short As[128 * 128];   // 32 KB
    __shared__ __align__(16) unsigned short Bs[128 * 128];   // 32 KB
    __shared__ float sh_hv[2][128];
    __shared__ float sh_part[2][128];

    const int tid = threadIdx.x;
    const int hb = blockIdx.x & 15;
    const int sb = blockIdx.x >> 4;
    const int s0 = sb * 128, h0 = hb * 128;
    const int wv = tid >> 6, lane = tid & 63;
    const int wm = wv >> 1, wn = wv & 1;

    // Staging: 64 chunks of 1KB (A: 0..31, B: 32..63). Round r (0..15):
    // chunk c = r*4 + wv. Chunk covers 4 rows of 256B; lane>>4 = row-in-chunk,
    // lane&15 = 16B slot. Source slot pre-XORed with (row&15).
    const unsigned short* srcP[16];
    unsigned short* dstP[16];
    #pragma unroll
    for (int r = 0; r < 16; r++) {
        const int c = r * 4 + wv;
        const int ism = (c < 32) ? c : (c - 32);
        const int row = ism * 4 + (lane >> 4);
        const int k0 = (((lane & 15) ^ (row & 15)) * 8);
        if (c < 32) {
            srcP[r] = encbf + (size_t)(s0 + row) * 2048 + k0;
            dstP[r] = &As[c * 512];
        } else {
            srcP[r] = wbf + (size_t)(h0 + row) * 2048 + k0;
            dstP[r] = &Bs[(c - 32) * 512];
        }
    }

    f32x4 acc[4][4];
    #pragma unroll
    for (int m = 0; m < 4; m++)
        #pragma unroll
        for (int n = 0; n < 4; n++)
            acc[m][n] = (f32x4){0.f, 0.f, 0.f, 0.f};

    const int swz = (lane & 15) << 4;          // XOR key = (row&15)<<4, row%16 == lane&15
    const int hi16 = (lane >> 4) * 16;

    for (int kt = 0; kt < 2048; kt += 128) {
        __syncthreads();
        #pragma unroll
        for (int r = 0; r < 16; r++)
            gload16(srcP[r] + kt, dstP[r]);
        __syncthreads();

        #pragma unroll
        for (int half = 0; half < 2; half++) {
            frag_t af[2][4], bq[2][4];
            #pragma unroll
            for (int k2 = 0; k2 < 2; k2++) {
                const int ks = half * 2 + k2;
                const int lo = (ks * 64 + hi16) ^ swz;
                #pragma unroll
                for (int m = 0; m < 4; m++) {
                    const int rowa = wm * 64 + m * 16 + (lane & 15);
                    af[k2][m] = *reinterpret_cast<const frag_t*>(
                        reinterpret_cast<const char*>(As) + rowa * 256 + lo);
                    const int rowb = wn * 64 + m * 16 + (lane & 15);
                    bq[k2][m] = *reinterpret_cast<const frag_t*>(
                        reinterpret_cast<const char*>(Bs) + rowb * 256 + lo);
                }
            }
            #pragma unroll
            for (int k2 = 0; k2 < 2; k2++)
                #pragma unroll
                for (int m = 0; m < 4; m++)
                    #pragma unroll
                    for (int n = 0; n < 4; n++)
                        acc[m][n] = __builtin_amdgcn_mfma_f32_16x16x32_bf16(
                            af[k2][m], bq[k2][n], acc[m][n], 0, 0, 0);
        }
    }

    if (tid < 128) { sh_hv[0][tid] = h_pre[h0 + tid]; sh_hv[1][tid] = v_attn[h0 + tid]; }
    __syncthreads();

    float ps[4][4];
    #pragma unroll
    for (int m = 0; m < 4; m++)
        #pragma unroll
        for (int r = 0; r < 4; r++) ps[m][r] = 0.f;

    #pragma unroll
    for (int m = 0; m < 4; m++) {
        #pragma unroll
        for (int n = 0; n < 4; n++) {
            const int hc = wn * 64 + n * 16 + (lane & 15);
            const float hp = sh_hv[0][hc], vvv = sh_hv[1][hc];
            #pragma unroll
            for (int r = 0; r < 4; r++) {
                float e = tanhf(acc[m][n][r] + hp);
                ps[m][r] += e * vvv;
            }
        }
    }
    #pragma unroll
    for (int m = 0; m < 4; m++)
        #pragma unroll
        for (int r = 0; r < 4; r++) {
            float p = ps[m][r];
            #pragma unroll
            for (int off = 1; off < 16; off <<= 1) p += __shfl_xor(p, off);
            ps[m][r] = p;
        }
    if ((lane & 15) == 0) {
        const int grp = lane >> 4;
        #pragma unroll
        for (int m = 0; m < 4; m++)
            #pragma unroll
            for (int r = 0; r < 4; r++)
                sh_part[wn][wm * 64 + m * 16 + grp * 4 + r] = ps[m][r];
    }
    __syncthreads();
    if (tid < 128)
        pscore[hb * SEQL + s0 + tid] = sh_part[0][tid] + sh_part[1][tid];
}

// ---------------------------------------------------------------------------
// K_C: reduce 16 partial score tiles + softmax over 4096 (one block)
__global__ __launch_bounds__(1024)
void k_softmax(const float* __restrict__ pscore, float* __restrict__ attnw)
{
    __shared__ float red[16];
    __shared__ float bcast;
    const int t = threadIdx.x, wv = t >> 6, lane = t & 63;
    float s[4];
    #pragma unroll
    for (int q = 0; q < 4; q++) {
        const int idx = q * 1024 + t;
        float a = 0.f;
        #pragma unroll
        for (int p = 0; p < 16; p++) a += pscore[p * SEQL + idx];
        s[q] = a;
    }
    float mx = fmaxf(fmaxf(s[0], s[1]), fmaxf(s[2], s[3]));
    #pragma unroll
    for (int off = 32; off; off >>= 1) mx = fmaxf(mx, __shfl_xor(mx, off));
    if (!lane) red[wv] = mx;
    __syncthreads();
    if (t == 0) {
        float m = red[0];
        for (int i = 1; i < 16; i++) m = fmaxf(m, red[i]);
        bcast = m;
    }
    __syncthreads();
    const float bm = bcast;
    float e[4], sum = 0.f;
    #pragma unroll
    for (int q = 0; q < 4; q++) { e[q] = __expf(s[q] - bm); sum += e[q]; }
    #pragma unroll
    for (int off = 32; off; off >>= 1) sum += __shfl_xor(sum, off);
    __syncthreads();
    if (!lane) red[wv] = sum;
    __syncthreads();
    if (t == 0) {
        float m = 0.f;
        for (int i = 0; i < 16; i++) m += red[i];
        bcast = m;
    }
    __syncthreads();
    const float inv = 1.f / bcast;
    #pragma unroll
    for (int q = 0; q < 4; q++) attnw[q * 1024 + t] = e[q] * inv;
}

// ---------------------------------------------------------------------------
// K_D: pweight[blk][h] = sum_{s in 8-chunk} a[s]*encbf[s,h]  (512 blocks)
__global__ __launch_bounds__(256)
void k_weighted_part(const unsigned short* __restrict__ encbf,
                     const float* __restrict__ attnw, float* __restrict__ pweight)
{
    const int blk = blockIdx.x;
    const int t = threadIdx.x;
    const int sbase = blk * 8;
    float acc[8];
    #pragma unroll
    for (int i = 0; i < 8; i++) acc[i] = 0.f;
    #pragma unroll
    for (int s = 0; s < 8; s++) {
        const float a = attnw[sbase + s];
        u16x8 v = *reinterpret_cast<const u16x8*>(encbf + (size_t)(sbase + s) * 2048 + t * 8);
        #pragma unroll
        for (int i = 0; i < 8; i++) acc[i] += a * bf2f(v[i]);
    }
    #pragma unroll
    for (int i = 0; i < 8; i++)
        pweight[(size_t)blk * 2048 + t * 8 + i] = acc[i];
}

// K_E: weighted[h] = sum over 512 pweight rows (64 blocks, 8 threads/h)
__global__ __launch_bounds__(256)
void k_weighted_reduce(const float* __restrict__ pweight, float* __restrict__ weighted)
{
    const int t = threadIdx.x;
    const int h = blockIdx.x * 32 + (t >> 3);
    const int slot = t & 7;
    float acc = 0.f;
    #pragma unroll 8
    for (int p = slot; p < 512; p += 8) acc += pweight[(size_t)p * 2048 + h];
    acc += __shfl_down(acc, 4);
    acc += __shfl_down(acc, 2);
    acc += __shfl_down(acc, 1);
    if (slot == 0) weighted[h] = acc;
}

// ---------------------------------------------------------------------------
// K_F: blocks 0..2047: finish gates with Wih[:,512:2560]@weighted + LSTM for t=blk.
//      blocks 2048..2175: out right-half: dout[n] = b_out[n] + Wout[n,2048:]@weighted
__global__ __launch_bounds__(256)
void k_gates_lstm_outR(const float* __restrict__ Wih, const float* __restrict__ weighted,
                       const float* __restrict__ gates, const float* __restrict__ c0,
                       const float* __restrict__ Wout, const float* __restrict__ b_out,
                       float* __restrict__ dout)
{
    __shared__ float sh[4];
    const int wv = threadIdx.x >> 6, lane = threadIdx.x & 63;
    if (blockIdx.x < 2048) {
        const int t = blockIdx.x;
        const int j = t + 2048 * wv;
        const float* Wr = Wih + (size_t)j * 2560 + 512;
        float s = 0.f;
        #pragma unroll
        for (int i = 0; i < 8; i++) {
            int c = i * 256 + lane * 4;
            float4 wvv = *reinterpret_cast<const float4*>(Wr + c);
            float4 hv = *reinterpret_cast<const float4*>(weighted + c);
            s += dot4(wvv, hv);
        }
        s = wave_sum(s);
        if (lane == 0) sh[wv] = s + gates[j];
        __syncthreads();
        if (threadIdx.x == 0) {
            const float gi = sh[0], gf = sh[1], gg = sh[2], go = sh[3];
            const float si = 1.f / (1.f + __expf(-gi));
            const float sf = 1.f / (1.f + __expf(-gf));
            const float so = 1.f / (1.f + __expf(-go));
            const float c = sf * c0[t] + si * tanhf(gg);
            const float h = so * tanhf(c);
            dout[512 + t]  = h;
            dout[2560 + t] = c;
        }
    } else {
        const int n = (blockIdx.x - 2048) * 4 + wv;   // 0..511
        const float* Wr = Wout + (size_t)n * 4096 + 2048;
        float s = 0.f;
        #pragma unroll
        for (int i = 0; i < 8; i++) {
            int c = i * 256 + lane * 4;
            float4 wvv = *reinterpret_cast<const float4*>(Wr + c);
            float4 hv = *reinterpret_cast<const float4*>(weighted + c);
            s += dot4(wvv, hv);
        }
        s = wave_sum(s);
        if (lane == 0) dout[n] = s + b_out[n];
    }
}

// ---------------------------------------------------------------------------
// K_G: dout[n] += Wout[n,0:2048] @ h_n
__global__ __launch_bounds__(256)
void k_out_left(const float* __restrict__ Wout, const float* __restrict__ hn,
                float* __restrict__ dout)
{
    const int n = (blockIdx.x * 256 + threadIdx.x) >> 6;   // 0..511
    const int lane = threadIdx.x & 63;
    const float* Wr = Wout + (size_t)n * 4096;
    float s = 0.f;
    #pragma unroll
    for (int i = 0; i < 8; i++) {
        int c = i * 256 + lane * 4;
        float4 wv = *reinterpret_cast<const float4*>(Wr + c);
        float4 hv = *reinterpret_cast<const float4*>(hn + c);
        s += dot4(wv, hv);
    }
    s = wave_sum(s);
    if (lane == 0) dout[n] += s;
}

// ---------------------------------------------------------------------------
extern "C" void kernel_launch(void* const* d_in, const int* in_sizes, int n_in,
                              void* d_out, int out_size, void* d_ws, size_t ws_size,
                              hipStream_t stream)
{
    const float* x        = (const float*)d_in[0];
    const float* ih       = (const float*)d_in[1];
    const float* ic       = (const float*)d_in[2];
    const float* enc      = (const float*)d_in[3];   // [4096,2048]
    const float* Wattn    = (const float*)d_in[4];   // [2048,4096]
    const float* b_attn   = (const float*)d_in[5];
    const float* v_attn   = (const float*)d_in[6];
    const float* Wih      = (const float*)d_in[7];   // [8192,2560]
    const float* Whh      = (const float*)d_in[8];   // [8192,2048]
    const float* b_ih     = (const float*)d_in[9];
    const float* b_hh     = (const float*)d_in[10];
    const float* Wout     = (const float*)d_in[11];  // [512,4096]
    const float* b_out    = (const float*)d_in[12];
    float* dout = (float*)d_out;   // [out 512][h_n 2048][c_n 2048]

    // ws: encbf 16MB | wbf 8MB (reused as pweight after K_B) | f32 scratch
    unsigned short* encbf = (unsigned short*)d_ws;                 // 8,388,608 u16
    unsigned short* wbf   = encbf + (size_t)8388608;               // 4,194,304 u16
    float* pweight  = (float*)wbf;        // 512*2048 f32 overlay (wbf dead after K_B)
    float* wsf      = (float*)(wbf + (size_t)4194304);
    float* h_pre    = wsf;                 // 2048
    float* gates    = wsf + 2048;          // 8192
    float* pscore   = wsf + 10240;         // 16*4096
    float* attnw    = wsf + 75776;         // 4096
    float* weighted = wsf + 79872;         // 2048

    k_conv_hpre_gates<<<8704, 256, 0, stream>>>(enc, Wattn, b_attn, ih,
                                                Wih, Whh, b_ih, b_hh, x,
                                                encbf, wbf, h_pre, gates);
    k_energy2<<<512, 256, 0, stream>>>(encbf, wbf, h_pre, v_attn, pscore);
    k_softmax<<<1, 1024, 0, stream>>>(pscore, attnw);
    k_weighted_part<<<512, 256, 0, stream>>>(encbf, attnw, pweight);
    k_weighted_reduce<<<64, 256, 0, stream>>>(pweight, weighted);
    k_gates_lstm_outR<<<2176, 256, 0, stream>>>(Wih, weighted, gates, ic,
                                                Wout, b_out, dout);
    k_out_left<<<128, 256, 0, stream>>>(Wout, dout + 512, dout);
}

// Round 10
// 122.459 us; speedup vs baseline: 1.1583x; 1.1583x over previous
//
#include <hip/hip_runtime.h>
#include <hip/hip_bf16.h>
#include <math.h>

// AttentionDecoder — Bahdanau attention + 1-step LSTM + out proj.
// SEQ=4096, H=2048, NF=512. All f32 in/out.
//
// R10: R6 build with ONE change: energy GEMM -> BK=32 double-buffered with
// prefetch-at-loop-top and a single __syncthreads per iteration (T3-minimum
// template, conservative barrier). LDS 32KB+epi (2 blocks/CU preserved).
// BK=32 fragment reads are 2-way bank aliased (free, m136) -> linear LDS,
// no swizzle, simpler staging.

#define HIDDEN 2048
#define SEQL   4096
#define NFEAT  512

typedef __attribute__((ext_vector_type(8))) short frag_t;   // 8 bf16
typedef __attribute__((ext_vector_type(8))) unsigned short u16x8;
typedef __attribute__((ext_vector_type(4))) float f32x4;

__device__ __forceinline__ unsigned short f2bf(float f) {
    union { float f; unsigned int u; } c; c.f = f;
    unsigned int r = c.u + 0x7fffu + ((c.u >> 16) & 1u);   // RNE
    return (unsigned short)(r >> 16);
}

__device__ __forceinline__ float bf2f(unsigned short u) {
    union { unsigned int u; float f; } c; c.u = (unsigned int)u << 16;
    return c.f;
}

__device__ __forceinline__ float wave_sum(float s) {
    #pragma unroll
    for (int off = 32; off; off >>= 1) s += __shfl_down(s, off);
    return s;
}

__device__ __forceinline__ float dot4(float4 a, float4 b) {
    return a.x*b.x + a.y*b.y + a.z*b.z + a.w*b.w;
}

__device__ __forceinline__ void gload16(const unsigned short* g, unsigned short* l) {
    __builtin_amdgcn_global_load_lds(
        (const __attribute__((address_space(1))) unsigned int*)g,
        (__attribute__((address_space(3))) unsigned int*)l, 16, 0, 0);
}

// ---------------------------------------------------------------------------
// K_A: blocks 0..4095   : enc f32->bf16
//      blocks 4096..6143: Wattn[:,2048:] f32->bf16
//      blocks 6144..6655: h_pre gemv (4 rows/block, one per wave)
//      blocks 6656..8703: gates gemv (4 rows/block):
//                         gates[j] = b_ih+b_hh + Wih[j,0:512]@x + Whh[j]@h0
__global__ __launch_bounds__(256)
void k_conv_hpre_gates(const float* __restrict__ enc, const float* __restrict__ Wattn,
                       const float* __restrict__ b_attn, const float* __restrict__ h0,
                       const float* __restrict__ Wih,  const float* __restrict__ Whh,
                       const float* __restrict__ b_ih, const float* __restrict__ b_hh,
                       const float* __restrict__ x,
                       unsigned short* __restrict__ encbf, unsigned short* __restrict__ wbf,
                       float* __restrict__ h_pre, float* __restrict__ gates)
{
    const int b = blockIdx.x;
    if (b < 6144) {
        const float* src;
        unsigned short* dst;
        if (b < 4096) {
            src = enc + (size_t)b * 2048;
            dst = encbf + (size_t)b * 2048;
        } else {
            const int r = b - 4096;
            src = Wattn + (size_t)r * 4096 + 2048;
            dst = wbf + (size_t)r * 2048;
        }
        const int t = threadIdx.x;
        float4 a = *reinterpret_cast<const float4*>(src + t * 8);
        float4 c = *reinterpret_cast<const float4*>(src + t * 8 + 4);
        u16x8 o;
        o[0] = f2bf(a.x); o[1] = f2bf(a.y); o[2] = f2bf(a.z); o[3] = f2bf(a.w);
        o[4] = f2bf(c.x); o[5] = f2bf(c.y); o[6] = f2bf(c.z); o[7] = f2bf(c.w);
        *reinterpret_cast<u16x8*>(dst + t * 8) = o;
    } else if (b < 6656) {
        const int gw = (b - 6144) * 4 + (threadIdx.x >> 6);   // row 0..2047
        const int lane = threadIdx.x & 63;
        const float* Wr = Wattn + (size_t)gw * 4096;
        float s = 0.f;
        #pragma unroll
        for (int i = 0; i < 8; i++) {
            int c = i * 256 + lane * 4;
            float4 wv = *reinterpret_cast<const float4*>(Wr + c);
            float4 hv = *reinterpret_cast<const float4*>(h0 + c);
            s += dot4(wv, hv);
        }
        s = wave_sum(s);
        if (lane == 0) h_pre[gw] = s + b_attn[gw];
    } else {
        const int j = (b - 6656) * 4 + (threadIdx.x >> 6);    // row 0..8191
        const int lane = threadIdx.x & 63;
        const float* W1 = Wih + (size_t)j * 2560;             // x part (cols 0..511)
        const float* W2 = Whh + (size_t)j * 2048;
        float s = 0.f;
        #pragma unroll
        for (int i = 0; i < 2; i++) {
            int c = i * 256 + lane * 4;
            float4 wv = *reinterpret_cast<const float4*>(W1 + c);
            float4 xv = *reinterpret_cast<const float4*>(x + c);
            s += dot4(wv, xv);
        }
        #pragma unroll
        for (int i = 0; i < 8; i++) {
            int c = i * 256 + lane * 4;
            float4 wv = *reinterpret_cast<const float4*>(W2 + c);
            float4 hv = *reinterpret_cast<const float4*>(h0 + c);
            s += dot4(wv, hv);
        }
        s = wave_sum(s);
        if (lane == 0) gates[j] = s + b_ih[j] + b_hh[j];
    }
}

// ---------------------------------------------------------------------------
// K_B: fused energy GEMM + tanh + v-dot reduction (bf16 inputs).
// C[s,h] = sum_k encbf[s,k] * wbf[h,k]    (NT, MFMA 16x16x32, f32 acc)
// pscore[hb][s] = sum_{h in tile} tanh(C[s,h] + h_pre[h]) * v[h]
// 128x128 tile, BK=32, DOUBLE-BUFFERED: prefetch tile t+1 at loop top,
// compute tile t, one __syncthreads per iter. Linear LDS (2-way banks, free).
__global__ __launch_bounds__(256)
void k_energy2(const unsigned short* __restrict__ encbf,
               const unsigned short* __restrict__ wbf,
               const float* __restrict__ h_pre, const float* __restrict__ v_attn,
               float* __restrict__ pscore)
{
    __shared__ __align__(16) unsigned short As[2][128 * 32];   // 2 x 8 KB
    __shared__ __align__(16) unsigned short Bs[2][128 * 32];   // 2 x 8 KB
    __shared__ float sh_hv[2][128];
    __shared__ float sh_part[2][128];

    const int tid = threadIdx.x;
    const int hb = blockIdx.x & 15;
    const int sb = blockIdx.x >> 4;
    const int s0 = sb * 128, h0 = hb * 128;
    const int wv = tid >> 6, lane = tid & 63;
    const int wm = wv >> 1, wn = wv & 1;

    // Staging (linear): tile = 128 rows x 32 cols bf16 = 8 KB = 8 chunks of 1KB.
    // Wave wv stages chunks {wv*2, wv*2+1} of A and of B.
    // Chunk c covers rows c*16..c*16+15; lane l -> row c*16 + (l>>2), col (l&3)*8.
    // LDS dest = chunk base + lane*16B (hardware rule) == row-major linear.  ✓
    const int ca = wv * 2, cb = wv * 2 + 1;
    const int rowa_st = (lane >> 2), cola_st = (lane & 3) * 8;
    const unsigned short* srcA0 = encbf + (size_t)(s0 + ca * 16 + rowa_st) * 2048 + cola_st;
    const unsigned short* srcA1 = encbf + (size_t)(s0 + cb * 16 + rowa_st) * 2048 + cola_st;
    const unsigned short* srcB0 = wbf  + (size_t)(h0 + ca * 16 + rowa_st) * 2048 + cola_st;
    const unsigned short* srcB1 = wbf  + (size_t)(h0 + cb * 16 + rowa_st) * 2048 + cola_st;

    f32x4 acc[4][4];
    #pragma unroll
    for (int m = 0; m < 4; m++)
        #pragma unroll
        for (int n = 0; n < 4; n++)
            acc[m][n] = (f32x4){0.f, 0.f, 0.f, 0.f};

    // fragment addresses (shorts): row*32 + (lane>>4)*8
    const int fr = lane & 15, fs = (lane >> 4) * 8;

    // prologue: stage tile 0 into buf 0
    gload16(srcA0, &As[0][ca * 512]);
    gload16(srcA1, &As[0][cb * 512]);
    gload16(srcB0, &Bs[0][ca * 512]);
    gload16(srcB1, &Bs[0][cb * 512]);
    __syncthreads();   // implicit vmcnt(0) drain: tile 0 landed

    int cur = 0;
    for (int t = 0; t < 64; ++t) {
        // prefetch tile t+1 into buf cur^1 (in flight during compute below)
        if (t < 63) {
            const int ko = (t + 1) * 32;
            gload16(srcA0 + ko, &As[cur ^ 1][ca * 512]);
            gload16(srcA1 + ko, &As[cur ^ 1][cb * 512]);
            gload16(srcB0 + ko, &Bs[cur ^ 1][ca * 512]);
            gload16(srcB1 + ko, &Bs[cur ^ 1][cb * 512]);
        }
        // compute tile t from buf cur
        frag_t af[4], bq[4];
        #pragma unroll
        for (int m = 0; m < 4; m++) {
            af[m] = *reinterpret_cast<const frag_t*>(
                &As[cur][(wm * 64 + m * 16 + fr) * 32 + fs]);
            bq[m] = *reinterpret_cast<const frag_t*>(
                &Bs[cur][(wn * 64 + m * 16 + fr) * 32 + fs]);
        }
        #pragma unroll
        for (int m = 0; m < 4; m++)
            #pragma unroll
            for (int n = 0; n < 4; n++)
                acc[m][n] = __builtin_amdgcn_mfma_f32_16x16x32_bf16(
                    af[m], bq[n], acc[m][n], 0, 0, 0);
        // one barrier per iter: drains prefetch (vmcnt0) + orders WAR on buf cur
        __syncthreads();
        cur ^= 1;
    }

    if (tid < 128) { sh_hv[0][tid] = h_pre[h0 + tid]; sh_hv[1][tid] = v_attn[h0 + tid]; }
    __syncthreads();

    float ps[4][4];
    #pragma unroll
    for (int m = 0; m < 4; m++)
        #pragma unroll
        for (int r = 0; r < 4; r++) ps[m][r] = 0.f;

    #pragma unroll
    for (int m = 0; m < 4; m++) {
        #pragma unroll
        for (int n = 0; n < 4; n++) {
            const int hc = wn * 64 + n * 16 + (lane & 15);
            const float hp = sh_hv[0][hc], vvv = sh_hv[1][hc];
            #pragma unroll
            for (int r = 0; r < 4; r++) {
                float e = tanhf(acc[m][n][r] + hp);
                ps[m][r] += e * vvv;
            }
        }
    }
    #pragma unroll
    for (int m = 0; m < 4; m++)
        #pragma unroll
        for (int r = 0; r < 4; r++) {
            float p = ps[m][r];
            #pragma unroll
            for (int off = 1; off < 16; off <<= 1) p += __shfl_xor(p, off);
            ps[m][r] = p;
        }
    if ((lane & 15) == 0) {
        const int grp = lane >> 4;
        #pragma unroll
        for (int m = 0; m < 4; m++)
            #pragma unroll
            for (int r = 0; r < 4; r++)
                sh_part[wn][wm * 64 + m * 16 + grp * 4 + r] = ps[m][r];
    }
    __syncthreads();
    if (tid < 128)
        pscore[hb * SEQL + s0 + tid] = sh_part[0][tid] + sh_part[1][tid];
}

// ---------------------------------------------------------------------------
// K_C: reduce 16 partial score tiles + softmax over 4096 (one block)
__global__ __launch_bounds__(1024)
void k_softmax(const float* __restrict__ pscore, float* __restrict__ attnw)
{
    __shared__ float red[16];
    __shared__ float bcast;
    const int t = threadIdx.x, wv = t >> 6, lane = t & 63;
    float s[4];
    #pragma unroll
    for (int q = 0; q < 4; q++) {
        const int idx = q * 1024 + t;
        float a = 0.f;
        #pragma unroll
        for (int p = 0; p < 16; p++) a += pscore[p * SEQL + idx];
        s[q] = a;
    }
    float mx = fmaxf(fmaxf(s[0], s[1]), fmaxf(s[2], s[3]));
    #pragma unroll
    for (int off = 32; off; off >>= 1) mx = fmaxf(mx, __shfl_xor(mx, off));
    if (!lane) red[wv] = mx;
    __syncthreads();
    if (t == 0) {
        float m = red[0];
        for (int i = 1; i < 16; i++) m = fmaxf(m, red[i]);
        bcast = m;
    }
    __syncthreads();
    const float bm = bcast;
    float e[4], sum = 0.f;
    #pragma unroll
    for (int q = 0; q < 4; q++) { e[q] = __expf(s[q] - bm); sum += e[q]; }
    #pragma unroll
    for (int off = 32; off; off >>= 1) sum += __shfl_xor(sum, off);
    __syncthreads();
    if (!lane) red[wv] = sum;
    __syncthreads();
    if (t == 0) {
        float m = 0.f;
        for (int i = 0; i < 16; i++) m += red[i];
        bcast = m;
    }
    __syncthreads();
    const float inv = 1.f / bcast;
    #pragma unroll
    for (int q = 0; q < 4; q++) attnw[q * 1024 + t] = e[q] * inv;
}

// ---------------------------------------------------------------------------
// K_D: pweight[blk][h] = sum_{s in 8-chunk} a[s]*encbf[s,h]  (512 blocks)
__global__ __launch_bounds__(256)
void k_weighted_part(const unsigned short* __restrict__ encbf,
                     const float* __restrict__ attnw, float* __restrict__ pweight)
{
    const int blk = blockIdx.x;
    const int t = threadIdx.x;
    const int sbase = blk * 8;
    float acc[8];
    #pragma unroll
    for (int i = 0; i < 8; i++) acc[i] = 0.f;
    #pragma unroll
    for (int s = 0; s < 8; s++) {
        const float a = attnw[sbase + s];
        u16x8 v = *reinterpret_cast<const u16x8*>(encbf + (size_t)(sbase + s) * 2048 + t * 8);
        #pragma unroll
        for (int i = 0; i < 8; i++) acc[i] += a * bf2f(v[i]);
    }
    #pragma unroll
    for (int i = 0; i < 8; i++)
        pweight[(size_t)blk * 2048 + t * 8 + i] = acc[i];
}

// K_E: weighted[h] = sum over 512 pweight rows (64 blocks, 8 threads/h)
__global__ __launch_bounds__(256)
void k_weighted_reduce(const float* __restrict__ pweight, float* __restrict__ weighted)
{
    const int t = threadIdx.x;
    const int h = blockIdx.x * 32 + (t >> 3);
    const int slot = t & 7;
    float acc = 0.f;
    #pragma unroll 8
    for (int p = slot; p < 512; p += 8) acc += pweight[(size_t)p * 2048 + h];
    acc += __shfl_down(acc, 4);
    acc += __shfl_down(acc, 2);
    acc += __shfl_down(acc, 1);
    if (slot == 0) weighted[h] = acc;
}

// ---------------------------------------------------------------------------
// K_F: blocks 0..2047: finish gates with Wih[:,512:2560]@weighted + LSTM for t=blk.
//      blocks 2048..2175: out right-half: dout[n] = b_out[n] + Wout[n,2048:]@weighted
__global__ __launch_bounds__(256)
void k_gates_lstm_outR(const float* __restrict__ Wih, const float* __restrict__ weighted,
                       const float* __restrict__ gates, const float* __restrict__ c0,
                       const float* __restrict__ Wout, const float* __restrict__ b_out,
                       float* __restrict__ dout)
{
    __shared__ float sh[4];
    const int wv = threadIdx.x >> 6, lane = threadIdx.x & 63;
    if (blockIdx.x < 2048) {
        const int t = blockIdx.x;
        const int j = t + 2048 * wv;
        const float* Wr = Wih + (size_t)j * 2560 + 512;
        float s = 0.f;
        #pragma unroll
        for (int i = 0; i < 8; i++) {
            int c = i * 256 + lane * 4;
            float4 wvv = *reinterpret_cast<const float4*>(Wr + c);
            float4 hv = *reinterpret_cast<const float4*>(weighted + c);
            s += dot4(wvv, hv);
        }
        s = wave_sum(s);
        if (lane == 0) sh[wv] = s + gates[j];
        __syncthreads();
        if (threadIdx.x == 0) {
            const float gi = sh[0], gf = sh[1], gg = sh[2], go = sh[3];
            const float si = 1.f / (1.f + __expf(-gi));
            const float sf = 1.f / (1.f + __expf(-gf));
            const float so = 1.f / (1.f + __expf(-go));
            const float c = sf * c0[t] + si * tanhf(gg);
            const float h = so * tanhf(c);
            dout[512 + t]  = h;
            dout[2560 + t] = c;
        }
    } else {
        const int n = (blockIdx.x - 2048) * 4 + wv;   // 0..511
        const float* Wr = Wout + (size_t)n * 4096 + 2048;
        float s = 0.f;
        #pragma unroll
        for (int i = 0; i < 8; i++) {
            int c = i * 256 + lane * 4;
            float4 wvv = *reinterpret_cast<const float4*>(Wr + c);
            float4 hv = *reinterpret_cast<const float4*>(weighted + c);
            s += dot4(wvv, hv);
        }
        s = wave_sum(s);
        if (lane == 0) dout[n] = s + b_out[n];
    }
}

// ---------------------------------------------------------------------------
// K_G: dout[n] += Wout[n,0:2048] @ h_n
__global__ __launch_bounds__(256)
void k_out_left(const float* __restrict__ Wout, const float* __restrict__ hn,
                float* __restrict__ dout)
{
    const int n = (blockIdx.x * 256 + threadIdx.x) >> 6;   // 0..511
    const int lane = threadIdx.x & 63;
    const float* Wr = Wout + (size_t)n * 4096;
    float s = 0.f;
    #pragma unroll
    for (int i = 0; i < 8; i++) {
        int c = i * 256 + lane * 4;
        float4 wv = *reinterpret_cast<const float4*>(Wr + c);
        float4 hv = *reinterpret_cast<const float4*>(hn + c);
        s += dot4(wv, hv);
    }
    s = wave_sum(s);
    if (lane == 0) dout[n] += s;
}

// ---------------------------------------------------------------------------
extern "C" void kernel_launch(void* const* d_in, const int* in_sizes, int n_in,
                              void* d_out, int out_size, void* d_ws, size_t ws_size,
                              hipStream_t stream)
{
    const float* x        = (const float*)d_in[0];
    const float* ih       = (const float*)d_in[1];
    const float* ic       = (const float*)d_in[2];
    const float* enc      = (const float*)d_in[3];   // [4096,2048]
    const float* Wattn    = (const float*)d_in[4];   // [2048,4096]
    const float* b_attn   = (const float*)d_in[5];
    const float* v_attn   = (const float*)d_in[6];
    const float* Wih      = (const float*)d_in[7];   // [8192,2560]
    const float* Whh      = (const float*)d_in[8];   // [8192,2048]
    const float* b_ih     = (const float*)d_in[9];
    const float* b_hh     = (const float*)d_in[10];
    const float* Wout     = (const float*)d_in[11];  // [512,4096]
    const float* b_out    = (const float*)d_in[12];
    float* dout = (float*)d_out;   // [out 512][h_n 2048][c_n 2048]

    // ws: encbf 16MB | wbf 8MB (reused as pweight after K_B) | f32 scratch
    unsigned short* encbf = (unsigned short*)d_ws;                 // 8,388,608 u16
    unsigned short* wbf   = encbf + (size_t)8388608;               // 4,194,304 u16
    float* pweight  = (float*)wbf;        // 512*2048 f32 overlay (wbf dead after K_B)
    float* wsf      = (float*)(wbf + (size_t)4194304);
    float* h_pre    = wsf;                 // 2048
    float* gates    = wsf + 2048;          // 8192
    float* pscore   = wsf + 10240;         // 16*4096
    float* attnw    = wsf + 75776;         // 4096
    float* weighted = wsf + 79872;         // 2048

    k_conv_hpre_gates<<<8704, 256, 0, stream>>>(enc, Wattn, b_attn, ih,
                                                Wih, Whh, b_ih, b_hh, x,
                                                encbf, wbf, h_pre, gates);
    k_energy2<<<512, 256, 0, stream>>>(encbf, wbf, h_pre, v_attn, pscore);
    k_softmax<<<1, 1024, 0, stream>>>(pscore, attnw);
    k_weighted_part<<<512, 256, 0, stream>>>(encbf, attnw, pweight);
    k_weighted_reduce<<<64, 256, 0, stream>>>(pweight, weighted);
    k_gates_lstm_outR<<<2176, 256, 0, stream>>>(Wih, weighted, gates, ic,
                                                Wout, b_out, dout);
    k_out_left<<<128, 256, 0, stream>>>(Wout, dout + 512, dout);
}

// Round 11
// 111.484 us; speedup vs baseline: 1.2723x; 1.0984x over previous
//
#include <hip/hip_runtime.h>
#include <hip/hip_bf16.h>
#include <math.h>

// AttentionDecoder — Bahdanau attention + 1-step LSTM + out proj.
// SEQ=4096, H=2048, NF=512. All f32 in/out.
//
// R11: R6 base (best passing, 108.0us) + softmax folded into weighted_part
// (each block recomputes identical softmax stats from L2-resident pscore;
// deterministic). 6 launches. Energy kernel frozen at its proven form after
// 5 failed schedule variants (BK=128: -occupancy; dbuf BK=32: 8-way bank
// conflicts; fusions: residency/correctness).

#define HIDDEN 2048
#define SEQL   4096
#define NFEAT  512

typedef __attribute__((ext_vector_type(8))) short frag_t;   // 8 bf16
typedef __attribute__((ext_vector_type(8))) unsigned short u16x8;
typedef __attribute__((ext_vector_type(4))) float f32x4;

__device__ __forceinline__ unsigned short f2bf(float f) {
    union { float f; unsigned int u; } c; c.f = f;
    unsigned int r = c.u + 0x7fffu + ((c.u >> 16) & 1u);   // RNE
    return (unsigned short)(r >> 16);
}

__device__ __forceinline__ float bf2f(unsigned short u) {
    union { unsigned int u; float f; } c; c.u = (unsigned int)u << 16;
    return c.f;
}

__device__ __forceinline__ float wave_sum(float s) {
    #pragma unroll
    for (int off = 32; off; off >>= 1) s += __shfl_down(s, off);
    return s;
}

__device__ __forceinline__ float dot4(float4 a, float4 b) {
    return a.x*b.x + a.y*b.y + a.z*b.z + a.w*b.w;
}

__device__ __forceinline__ void gload16(const unsigned short* g, unsigned short* l) {
    __builtin_amdgcn_global_load_lds(
        (const __attribute__((address_space(1))) unsigned int*)g,
        (__attribute__((address_space(3))) unsigned int*)l, 16, 0, 0);
}

// ---------------------------------------------------------------------------
// K_A: blocks 0..4095   : enc f32->bf16
//      blocks 4096..6143: Wattn[:,2048:] f32->bf16
//      blocks 6144..6655: h_pre gemv (4 rows/block, one per wave)
//      blocks 6656..8703: gates gemv (4 rows/block):
//                         gates[j] = b_ih+b_hh + Wih[j,0:512]@x + Whh[j]@h0
__global__ __launch_bounds__(256)
void k_conv_hpre_gates(const float* __restrict__ enc, const float* __restrict__ Wattn,
                       const float* __restrict__ b_attn, const float* __restrict__ h0,
                       const float* __restrict__ Wih,  const float* __restrict__ Whh,
                       const float* __restrict__ b_ih, const float* __restrict__ b_hh,
                       const float* __restrict__ x,
                       unsigned short* __restrict__ encbf, unsigned short* __restrict__ wbf,
                       float* __restrict__ h_pre, float* __restrict__ gates)
{
    const int b = blockIdx.x;
    if (b < 6144) {
        const float* src;
        unsigned short* dst;
        if (b < 4096) {
            src = enc + (size_t)b * 2048;
            dst = encbf + (size_t)b * 2048;
        } else {
            const int r = b - 4096;
            src = Wattn + (size_t)r * 4096 + 2048;
            dst = wbf + (size_t)r * 2048;
        }
        const int t = threadIdx.x;
        float4 a = *reinterpret_cast<const float4*>(src + t * 8);
        float4 c = *reinterpret_cast<const float4*>(src + t * 8 + 4);
        u16x8 o;
        o[0] = f2bf(a.x); o[1] = f2bf(a.y); o[2] = f2bf(a.z); o[3] = f2bf(a.w);
        o[4] = f2bf(c.x); o[5] = f2bf(c.y); o[6] = f2bf(c.z); o[7] = f2bf(c.w);
        *reinterpret_cast<u16x8*>(dst + t * 8) = o;
    } else if (b < 6656) {
        const int gw = (b - 6144) * 4 + (threadIdx.x >> 6);   // row 0..2047
        const int lane = threadIdx.x & 63;
        const float* Wr = Wattn + (size_t)gw * 4096;
        float s = 0.f;
        #pragma unroll
        for (int i = 0; i < 8; i++) {
            int c = i * 256 + lane * 4;
            float4 wv = *reinterpret_cast<const float4*>(Wr + c);
            float4 hv = *reinterpret_cast<const float4*>(h0 + c);
            s += dot4(wv, hv);
        }
        s = wave_sum(s);
        if (lane == 0) h_pre[gw] = s + b_attn[gw];
    } else {
        const int j = (b - 6656) * 4 + (threadIdx.x >> 6);    // row 0..8191
        const int lane = threadIdx.x & 63;
        const float* W1 = Wih + (size_t)j * 2560;             // x part (cols 0..511)
        const float* W2 = Whh + (size_t)j * 2048;
        float s = 0.f;
        #pragma unroll
        for (int i = 0; i < 2; i++) {
            int c = i * 256 + lane * 4;
            float4 wv = *reinterpret_cast<const float4*>(W1 + c);
            float4 xv = *reinterpret_cast<const float4*>(x + c);
            s += dot4(wv, xv);
        }
        #pragma unroll
        for (int i = 0; i < 8; i++) {
            int c = i * 256 + lane * 4;
            float4 wv = *reinterpret_cast<const float4*>(W2 + c);
            float4 hv = *reinterpret_cast<const float4*>(h0 + c);
            s += dot4(wv, hv);
        }
        s = wave_sum(s);
        if (lane == 0) gates[j] = s + b_ih[j] + b_hh[j];
    }
}

// ---------------------------------------------------------------------------
// K_B: fused energy GEMM + tanh + v-dot reduction (bf16 inputs). R2-proven.
// C[s,h] = sum_k encbf[s,k] * wbf[h,k]    (NT, MFMA 16x16x32, f32 acc)
// pscore[hb][s] = sum_{h in tile} tanh(C[s,h] + h_pre[h]) * v[h]
// 128x128 tile, BK=64, 4 waves 2x2. LDS linear dest (global_load_lds),
// XOR swizzle byte^=((row&7)<<4) realized by pre-swizzled per-lane source.
__global__ __launch_bounds__(256)
void k_energy2(const unsigned short* __restrict__ encbf,
               const unsigned short* __restrict__ wbf,
               const float* __restrict__ h_pre, const float* __restrict__ v_attn,
               float* __restrict__ pscore)
{
    __shared__ __align__(16) unsigned short As[128 * 64];
    __shared__ __align__(16) unsigned short Bs[128 * 64];
    __shared__ float sh_hv[2][128];
    __shared__ float sh_part[2][128];

    const int tid = threadIdx.x;
    const int hb = blockIdx.x & 15;
    const int sb = blockIdx.x >> 4;
    const int s0 = sb * 128, h0 = hb * 128;
    const int wv = tid >> 6, lane = tid & 63;
    const int wm = wv >> 1, wn = wv & 1;

    const unsigned short* srcA[4];
    const unsigned short* srcB[4];
    #pragma unroll
    for (int i = 0; i < 4; i++) {
        const int c = wv * 4 + i;
        const int row = c * 8 + (lane >> 3);
        const int k0 = ((lane & 7) ^ (row & 7)) * 8;
        srcA[i] = encbf + (size_t)(s0 + row) * 2048 + k0;
        srcB[i] = wbf  + (size_t)(h0 + row) * 2048 + k0;
    }

    f32x4 acc[4][4];
    #pragma unroll
    for (int m = 0; m < 4; m++)
        #pragma unroll
        for (int n = 0; n < 4; n++)
            acc[m][n] = (f32x4){0.f, 0.f, 0.f, 0.f};

    const int swz = (lane & 7) << 4;
    const int hi16 = (lane >> 4) * 16;

    for (int kt = 0; kt < 2048; kt += 64) {
        __syncthreads();
        #pragma unroll
        for (int i = 0; i < 4; i++) {
            const int c = wv * 4 + i;
            gload16(srcA[i] + kt, &As[c * 512]);
            gload16(srcB[i] + kt, &Bs[c * 512]);
        }
        __syncthreads();

        frag_t af[2][4], bq[2][4];
        #pragma unroll
        for (int ks = 0; ks < 2; ks++) {
            const int lo = (ks * 64 + hi16) ^ swz;
            #pragma unroll
            for (int m = 0; m < 4; m++) {
                const int rowa = wm * 64 + m * 16 + (lane & 15);
                af[ks][m] = *reinterpret_cast<const frag_t*>(
                    reinterpret_cast<const char*>(As) + rowa * 128 + lo);
                const int rowb = wn * 64 + m * 16 + (lane & 15);
                bq[ks][m] = *reinterpret_cast<const frag_t*>(
                    reinterpret_cast<const char*>(Bs) + rowb * 128 + lo);
            }
        }
        #pragma unroll
        for (int ks = 0; ks < 2; ks++)
            #pragma unroll
            for (int m = 0; m < 4; m++)
                #pragma unroll
                for (int n = 0; n < 4; n++)
                    acc[m][n] = __builtin_amdgcn_mfma_f32_16x16x32_bf16(
                        af[ks][m], bq[ks][n], acc[m][n], 0, 0, 0);
    }

    if (tid < 128) { sh_hv[0][tid] = h_pre[h0 + tid]; sh_hv[1][tid] = v_attn[h0 + tid]; }
    __syncthreads();

    float ps[4][4];
    #pragma unroll
    for (int m = 0; m < 4; m++)
        #pragma unroll
        for (int r = 0; r < 4; r++) ps[m][r] = 0.f;

    #pragma unroll
    for (int m = 0; m < 4; m++) {
        #pragma unroll
        for (int n = 0; n < 4; n++) {
            const int hc = wn * 64 + n * 16 + (lane & 15);
            const float hp = sh_hv[0][hc], vvv = sh_hv[1][hc];
            #pragma unroll
            for (int r = 0; r < 4; r++) {
                float e = tanhf(acc[m][n][r] + hp);
                ps[m][r] += e * vvv;
            }
        }
    }
    #pragma unroll
    for (int m = 0; m < 4; m++)
        #pragma unroll
        for (int r = 0; r < 4; r++) {
            float p = ps[m][r];
            #pragma unroll
            for (int off = 1; off < 16; off <<= 1) p += __shfl_xor(p, off);
            ps[m][r] = p;
        }
    if ((lane & 15) == 0) {
        const int grp = lane >> 4;
        #pragma unroll
        for (int m = 0; m < 4; m++)
            #pragma unroll
            for (int r = 0; r < 4; r++)
                sh_part[wn][wm * 64 + m * 16 + grp * 4 + r] = ps[m][r];
    }
    __syncthreads();
    if (tid < 128)
        pscore[hb * SEQL + s0 + tid] = sh_part[0][tid] + sh_part[1][tid];
}

// ---------------------------------------------------------------------------
// K_D: fused softmax + weighted partial (512 blocks).
// Every block recomputes the (identical, deterministic) softmax stats from
// pscore, then computes its own 8 attnw values and the weighted partial:
// pweight[blk][h] = sum_{s in 8-chunk} attnw[s] * encbf[s,h]
__global__ __launch_bounds__(256)
void k_weighted_part(const unsigned short* __restrict__ encbf,
                     const float* __restrict__ pscore, float* __restrict__ pweight)
{
    __shared__ float red[4];
    __shared__ float bcast;
    __shared__ float aw[8];
    const int blk = blockIdx.x;
    const int t = threadIdx.x;
    const int wv = t >> 6, lane = t & 63;
    const int sbase = blk * 8;

    // --- scores: thread t covers idx q*1024 + t*4 .. +3, q=0..3 (float4) ---
    float4 s4[4];
    #pragma unroll
    for (int q = 0; q < 4; q++) {
        float4 a = make_float4(0.f, 0.f, 0.f, 0.f);
        const int idx = q * 1024 + t * 4;
        #pragma unroll
        for (int p = 0; p < 16; p++) {
            float4 v = *reinterpret_cast<const float4*>(pscore + p * SEQL + idx);
            a.x += v.x; a.y += v.y; a.z += v.z; a.w += v.w;
        }
        s4[q] = a;
    }
    // --- block max ---
    float mx = -1e30f;
    #pragma unroll
    for (int q = 0; q < 4; q++)
        mx = fmaxf(mx, fmaxf(fmaxf(s4[q].x, s4[q].y), fmaxf(s4[q].z, s4[q].w)));
    #pragma unroll
    for (int off = 32; off; off >>= 1) mx = fmaxf(mx, __shfl_xor(mx, off));
    if (!lane) red[wv] = mx;
    __syncthreads();
    if (t == 0)
        bcast = fmaxf(fmaxf(red[0], red[1]), fmaxf(red[2], red[3]));
    __syncthreads();
    const float M = bcast;
    // --- block sum of exp ---
    float sum = 0.f;
    #pragma unroll
    for (int q = 0; q < 4; q++) {
        sum += __expf(s4[q].x - M) + __expf(s4[q].y - M)
             + __expf(s4[q].z - M) + __expf(s4[q].w - M);
    }
    #pragma unroll
    for (int off = 32; off; off >>= 1) sum += __shfl_xor(sum, off);
    __syncthreads();
    if (!lane) red[wv] = sum;
    __syncthreads();
    if (t == 0)
        bcast = red[0] + red[1] + red[2] + red[3];
    __syncthreads();
    const float inv = 1.f / bcast;
    // --- own 8 attention weights ---
    if (t < 8) {
        float a = 0.f;
        #pragma unroll
        for (int p = 0; p < 16; p++) a += pscore[p * SEQL + sbase + t];
        aw[t] = __expf(a - M) * inv;
    }
    __syncthreads();

    // --- weighted partial ---
    float acc[8];
    #pragma unroll
    for (int i = 0; i < 8; i++) acc[i] = 0.f;
    #pragma unroll
    for (int s = 0; s < 8; s++) {
        const float a = aw[s];
        u16x8 v = *reinterpret_cast<const u16x8*>(encbf + (size_t)(sbase + s) * 2048 + t * 8);
        #pragma unroll
        for (int i = 0; i < 8; i++) acc[i] += a * bf2f(v[i]);
    }
    #pragma unroll
    for (int i = 0; i < 8; i++)
        pweight[(size_t)blk * 2048 + t * 8 + i] = acc[i];
}

// K_E: weighted[h] = sum over 512 pweight rows (64 blocks, 8 threads/h)
__global__ __launch_bounds__(256)
void k_weighted_reduce(const float* __restrict__ pweight, float* __restrict__ weighted)
{
    const int t = threadIdx.x;
    const int h = blockIdx.x * 32 + (t >> 3);
    const int slot = t & 7;
    float acc = 0.f;
    #pragma unroll 8
    for (int p = slot; p < 512; p += 8) acc += pweight[(size_t)p * 2048 + h];
    acc += __shfl_down(acc, 4);
    acc += __shfl_down(acc, 2);
    acc += __shfl_down(acc, 1);
    if (slot == 0) weighted[h] = acc;
}

// ---------------------------------------------------------------------------
// K_F: blocks 0..2047: finish gates with Wih[:,512:2560]@weighted + LSTM for t=blk.
//      blocks 2048..2175: out right-half: dout[n] = b_out[n] + Wout[n,2048:]@weighted
__global__ __launch_bounds__(256)
void k_gates_lstm_outR(const float* __restrict__ Wih, const float* __restrict__ weighted,
                       const float* __restrict__ gates, const float* __restrict__ c0,
                       const float* __restrict__ Wout, const float* __restrict__ b_out,
                       float* __restrict__ dout)
{
    __shared__ float sh[4];
    const int wv = threadIdx.x >> 6, lane = threadIdx.x & 63;
    if (blockIdx.x < 2048) {
        const int t = blockIdx.x;
        const int j = t + 2048 * wv;
        const float* Wr = Wih + (size_t)j * 2560 + 512;
        float s = 0.f;
        #pragma unroll
        for (int i = 0; i < 8; i++) {
            int c = i * 256 + lane * 4;
            float4 wvv = *reinterpret_cast<const float4*>(Wr + c);
            float4 hv = *reinterpret_cast<const float4*>(weighted + c);
            s += dot4(wvv, hv);
        }
        s = wave_sum(s);
        if (lane == 0) sh[wv] = s + gates[j];
        __syncthreads();
        if (threadIdx.x == 0) {
            const float gi = sh[0], gf = sh[1], gg = sh[2], go = sh[3];
            const float si = 1.f / (1.f + __expf(-gi));
            const float sf = 1.f / (1.f + __expf(-gf));
            const float so = 1.f / (1.f + __expf(-go));
            const float c = sf * c0[t] + si * tanhf(gg);
            const float h = so * tanhf(c);
            dout[512 + t]  = h;
            dout[2560 + t] = c;
        }
    } else {
        const int n = (blockIdx.x - 2048) * 4 + wv;   // 0..511
        const float* Wr = Wout + (size_t)n * 4096 + 2048;
        float s = 0.f;
        #pragma unroll
        for (int i = 0; i < 8; i++) {
            int c = i * 256 + lane * 4;
            float4 wvv = *reinterpret_cast<const float4*>(Wr + c);
            float4 hv = *reinterpret_cast<const float4*>(weighted + c);
            s += dot4(wvv, hv);
        }
        s = wave_sum(s);
        if (lane == 0) dout[n] = s + b_out[n];
    }
}

// ---------------------------------------------------------------------------
// K_G: dout[n] += Wout[n,0:2048] @ h_n
__global__ __launch_bounds__(256)
void k_out_left(const float* __restrict__ Wout, const float* __restrict__ hn,
                float* __restrict__ dout)
{
    const int n = (blockIdx.x * 256 + threadIdx.x) >> 6;   // 0..511
    const int lane = threadIdx.x & 63;
    const float* Wr = Wout + (size_t)n * 4096;
    float s = 0.f;
    #pragma unroll
    for (int i = 0; i < 8; i++) {
        int c = i * 256 + lane * 4;
        float4 wv = *reinterpret_cast<const float4*>(Wr + c);
        float4 hv = *reinterpret_cast<const float4*>(hn + c);
        s += dot4(wv, hv);
    }
    s = wave_sum(s);
    if (lane == 0) dout[n] += s;
}

// ---------------------------------------------------------------------------
extern "C" void kernel_launch(void* const* d_in, const int* in_sizes, int n_in,
                              void* d_out, int out_size, void* d_ws, size_t ws_size,
                              hipStream_t stream)
{
    const float* x        = (const float*)d_in[0];
    const float* ih       = (const float*)d_in[1];
    const float* ic       = (const float*)d_in[2];
    const float* enc      = (const float*)d_in[3];   // [4096,2048]
    const float* Wattn    = (const float*)d_in[4];   // [2048,4096]
    const float* b_attn   = (const float*)d_in[5];
    const float* v_attn   = (const float*)d_in[6];
    const float* Wih      = (const float*)d_in[7];   // [8192,2560]
    const float* Whh      = (const float*)d_in[8];   // [8192,2048]
    const float* b_ih     = (const float*)d_in[9];
    const float* b_hh     = (const float*)d_in[10];
    const float* Wout     = (const float*)d_in[11];  // [512,4096]
    const float* b_out    = (const float*)d_in[12];
    float* dout = (float*)d_out;   // [out 512][h_n 2048][c_n 2048]

    // ws: encbf 16MB | wbf 8MB (reused as pweight after K_B) | f32 scratch
    unsigned short* encbf = (unsigned short*)d_ws;                 // 8,388,608 u16
    unsigned short* wbf   = encbf + (size_t)8388608;               // 4,194,304 u16
    float* pweight  = (float*)wbf;        // 512*2048 f32 overlay (wbf dead after K_B)
    float* wsf      = (float*)(wbf + (size_t)4194304);
    float* h_pre    = wsf;                 // 2048
    float* gates    = wsf + 2048;          // 8192
    float* pscore   = wsf + 10240;         // 16*4096
    float* weighted = wsf + 79872;         // 2048

    k_conv_hpre_gates<<<8704, 256, 0, stream>>>(enc, Wattn, b_attn, ih,
                                                Wih, Whh, b_ih, b_hh, x,
                                                encbf, wbf, h_pre, gates);
    k_energy2<<<512, 256, 0, stream>>>(encbf, wbf, h_pre, v_attn, pscore);
    k_weighted_part<<<512, 256, 0, stream>>>(encbf, pscore, pweight);
    k_weighted_reduce<<<64, 256, 0, stream>>>(pweight, weighted);
    k_gates_lstm_outR<<<2176, 256, 0, stream>>>(Wih, weighted, gates, ic,
                                                Wout, b_out, dout);
    k_out_left<<<128, 256, 0, stream>>>(Wout, dout + 512, dout);
}

// Round 12
// 107.819 us; speedup vs baseline: 1.3155x; 1.0340x over previous
//
#include <hip/hip_runtime.h>
#include <hip/hip_bf16.h>
#include <math.h>

// AttentionDecoder — Bahdanau attention + 1-step LSTM + out proj.
// SEQ=4096, H=2048, NF=512. All f32 in/out.
//
// R12: byte-identical revert to R6 (session best, 108.0us).
//  - K_A: conv(enc,Wattn-right->bf16) + h_pre gemv + gates gemv.
//  - K_B: R2-proven energy kernel (49.4us, MfmaUtil 27%, 0 conflicts,
//    structure-bound: same time at FETCH=0; frozen after 6 failed variants).
//  - Tail: separate softmax (1-block, launch-latency floor), weighted
//    part/reduce, gates+LSTM+outR, out_left.

#define HIDDEN 2048
#define SEQL   4096
#define NFEAT  512

typedef __attribute__((ext_vector_type(8))) short frag_t;   // 8 bf16
typedef __attribute__((ext_vector_type(8))) unsigned short u16x8;
typedef __attribute__((ext_vector_type(4))) float f32x4;

__device__ __forceinline__ unsigned short f2bf(float f) {
    union { float f; unsigned int u; } c; c.f = f;
    unsigned int r = c.u + 0x7fffu + ((c.u >> 16) & 1u);   // RNE
    return (unsigned short)(r >> 16);
}

__device__ __forceinline__ float bf2f(unsigned short u) {
    union { unsigned int u; float f; } c; c.u = (unsigned int)u << 16;
    return c.f;
}

__device__ __forceinline__ float wave_sum(float s) {
    #pragma unroll
    for (int off = 32; off; off >>= 1) s += __shfl_down(s, off);
    return s;
}

__device__ __forceinline__ float dot4(float4 a, float4 b) {
    return a.x*b.x + a.y*b.y + a.z*b.z + a.w*b.w;
}

__device__ __forceinline__ void gload16(const unsigned short* g, unsigned short* l) {
    __builtin_amdgcn_global_load_lds(
        (const __attribute__((address_space(1))) unsigned int*)g,
        (__attribute__((address_space(3))) unsigned int*)l, 16, 0, 0);
}

// ---------------------------------------------------------------------------
// K_A: blocks 0..4095   : enc f32->bf16
//      blocks 4096..6143: Wattn[:,2048:] f32->bf16
//      blocks 6144..6655: h_pre gemv (4 rows/block, one per wave)
//      blocks 6656..8703: gates gemv (4 rows/block):
//                         gates[j] = b_ih+b_hh + Wih[j,0:512]@x + Whh[j]@h0
__global__ __launch_bounds__(256)
void k_conv_hpre_gates(const float* __restrict__ enc, const float* __restrict__ Wattn,
                       const float* __restrict__ b_attn, const float* __restrict__ h0,
                       const float* __restrict__ Wih,  const float* __restrict__ Whh,
                       const float* __restrict__ b_ih, const float* __restrict__ b_hh,
                       const float* __restrict__ x,
                       unsigned short* __restrict__ encbf, unsigned short* __restrict__ wbf,
                       float* __restrict__ h_pre, float* __restrict__ gates)
{
    const int b = blockIdx.x;
    if (b < 6144) {
        const float* src;
        unsigned short* dst;
        if (b < 4096) {
            src = enc + (size_t)b * 2048;
            dst = encbf + (size_t)b * 2048;
        } else {
            const int r = b - 4096;
            src = Wattn + (size_t)r * 4096 + 2048;
            dst = wbf + (size_t)r * 2048;
        }
        const int t = threadIdx.x;
        float4 a = *reinterpret_cast<const float4*>(src + t * 8);
        float4 c = *reinterpret_cast<const float4*>(src + t * 8 + 4);
        u16x8 o;
        o[0] = f2bf(a.x); o[1] = f2bf(a.y); o[2] = f2bf(a.z); o[3] = f2bf(a.w);
        o[4] = f2bf(c.x); o[5] = f2bf(c.y); o[6] = f2bf(c.z); o[7] = f2bf(c.w);
        *reinterpret_cast<u16x8*>(dst + t * 8) = o;
    } else if (b < 6656) {
        const int gw = (b - 6144) * 4 + (threadIdx.x >> 6);   // row 0..2047
        const int lane = threadIdx.x & 63;
        const float* Wr = Wattn + (size_t)gw * 4096;
        float s = 0.f;
        #pragma unroll
        for (int i = 0; i < 8; i++) {
            int c = i * 256 + lane * 4;
            float4 wv = *reinterpret_cast<const float4*>(Wr + c);
            float4 hv = *reinterpret_cast<const float4*>(h0 + c);
            s += dot4(wv, hv);
        }
        s = wave_sum(s);
        if (lane == 0) h_pre[gw] = s + b_attn[gw];
    } else {
        const int j = (b - 6656) * 4 + (threadIdx.x >> 6);    // row 0..8191
        const int lane = threadIdx.x & 63;
        const float* W1 = Wih + (size_t)j * 2560;             // x part (cols 0..511)
        const float* W2 = Whh + (size_t)j * 2048;
        float s = 0.f;
        #pragma unroll
        for (int i = 0; i < 2; i++) {
            int c = i * 256 + lane * 4;
            float4 wv = *reinterpret_cast<const float4*>(W1 + c);
            float4 xv = *reinterpret_cast<const float4*>(x + c);
            s += dot4(wv, xv);
        }
        #pragma unroll
        for (int i = 0; i < 8; i++) {
            int c = i * 256 + lane * 4;
            float4 wv = *reinterpret_cast<const float4*>(W2 + c);
            float4 hv = *reinterpret_cast<const float4*>(h0 + c);
            s += dot4(wv, hv);
        }
        s = wave_sum(s);
        if (lane == 0) gates[j] = s + b_ih[j] + b_hh[j];
    }
}

// ---------------------------------------------------------------------------
// K_B: fused energy GEMM + tanh + v-dot reduction (bf16 inputs). R2-proven.
// C[s,h] = sum_k encbf[s,k] * wbf[h,k]    (NT, MFMA 16x16x32, f32 acc)
// pscore[hb][s] = sum_{h in tile} tanh(C[s,h] + h_pre[h]) * v[h]
// 128x128 tile, BK=64, 4 waves 2x2. LDS linear dest (global_load_lds),
// XOR swizzle byte^=((row&7)<<4) realized by pre-swizzled per-lane source.
__global__ __launch_bounds__(256)
void k_energy2(const unsigned short* __restrict__ encbf,
               const unsigned short* __restrict__ wbf,
               const float* __restrict__ h_pre, const float* __restrict__ v_attn,
               float* __restrict__ pscore)
{
    __shared__ __align__(16) unsigned short As[128 * 64];
    __shared__ __align__(16) unsigned short Bs[128 * 64];
    __shared__ float sh_hv[2][128];
    __shared__ float sh_part[2][128];

    const int tid = threadIdx.x;
    const int hb = blockIdx.x & 15;
    const int sb = blockIdx.x >> 4;
    const int s0 = sb * 128, h0 = hb * 128;
    const int wv = tid >> 6, lane = tid & 63;
    const int wm = wv >> 1, wn = wv & 1;

    const unsigned short* srcA[4];
    const unsigned short* srcB[4];
    #pragma unroll
    for (int i = 0; i < 4; i++) {
        const int c = wv * 4 + i;
        const int row = c * 8 + (lane >> 3);
        const int k0 = ((lane & 7) ^ (row & 7)) * 8;
        srcA[i] = encbf + (size_t)(s0 + row) * 2048 + k0;
        srcB[i] = wbf  + (size_t)(h0 + row) * 2048 + k0;
    }

    f32x4 acc[4][4];
    #pragma unroll
    for (int m = 0; m < 4; m++)
        #pragma unroll
        for (int n = 0; n < 4; n++)
            acc[m][n] = (f32x4){0.f, 0.f, 0.f, 0.f};

    const int swz = (lane & 7) << 4;
    const int hi16 = (lane >> 4) * 16;

    for (int kt = 0; kt < 2048; kt += 64) {
        __syncthreads();
        #pragma unroll
        for (int i = 0; i < 4; i++) {
            const int c = wv * 4 + i;
            gload16(srcA[i] + kt, &As[c * 512]);
            gload16(srcB[i] + kt, &Bs[c * 512]);
        }
        __syncthreads();

        frag_t af[2][4], bq[2][4];
        #pragma unroll
        for (int ks = 0; ks < 2; ks++) {
            const int lo = (ks * 64 + hi16) ^ swz;
            #pragma unroll
            for (int m = 0; m < 4; m++) {
                const int rowa = wm * 64 + m * 16 + (lane & 15);
                af[ks][m] = *reinterpret_cast<const frag_t*>(
                    reinterpret_cast<const char*>(As) + rowa * 128 + lo);
                const int rowb = wn * 64 + m * 16 + (lane & 15);
                bq[ks][m] = *reinterpret_cast<const frag_t*>(
                    reinterpret_cast<const char*>(Bs) + rowb * 128 + lo);
            }
        }
        #pragma unroll
        for (int ks = 0; ks < 2; ks++)
            #pragma unroll
            for (int m = 0; m < 4; m++)
                #pragma unroll
                for (int n = 0; n < 4; n++)
                    acc[m][n] = __builtin_amdgcn_mfma_f32_16x16x32_bf16(
                        af[ks][m], bq[ks][n], acc[m][n], 0, 0, 0);
    }

    if (tid < 128) { sh_hv[0][tid] = h_pre[h0 + tid]; sh_hv[1][tid] = v_attn[h0 + tid]; }
    __syncthreads();

    float ps[4][4];
    #pragma unroll
    for (int m = 0; m < 4; m++)
        #pragma unroll
        for (int r = 0; r < 4; r++) ps[m][r] = 0.f;

    #pragma unroll
    for (int m = 0; m < 4; m++) {
        #pragma unroll
        for (int n = 0; n < 4; n++) {
            const int hc = wn * 64 + n * 16 + (lane & 15);
            const float hp = sh_hv[0][hc], vvv = sh_hv[1][hc];
            #pragma unroll
            for (int r = 0; r < 4; r++) {
                float e = tanhf(acc[m][n][r] + hp);
                ps[m][r] += e * vvv;
            }
        }
    }
    #pragma unroll
    for (int m = 0; m < 4; m++)
        #pragma unroll
        for (int r = 0; r < 4; r++) {
            float p = ps[m][r];
            #pragma unroll
            for (int off = 1; off < 16; off <<= 1) p += __shfl_xor(p, off);
            ps[m][r] = p;
        }
    if ((lane & 15) == 0) {
        const int grp = lane >> 4;
        #pragma unroll
        for (int m = 0; m < 4; m++)
            #pragma unroll
            for (int r = 0; r < 4; r++)
                sh_part[wn][wm * 64 + m * 16 + grp * 4 + r] = ps[m][r];
    }
    __syncthreads();
    if (tid < 128)
        pscore[hb * SEQL + s0 + tid] = sh_part[0][tid] + sh_part[1][tid];
}

// ---------------------------------------------------------------------------
// K_C: reduce 16 partial score tiles + softmax over 4096 (one block)
__global__ __launch_bounds__(1024)
void k_softmax(const float* __restrict__ pscore, float* __restrict__ attnw)
{
    __shared__ float red[16];
    __shared__ float bcast;
    const int t = threadIdx.x, wv = t >> 6, lane = t & 63;
    float s[4];
    #pragma unroll
    for (int q = 0; q < 4; q++) {
        const int idx = q * 1024 + t;
        float a = 0.f;
        #pragma unroll
        for (int p = 0; p < 16; p++) a += pscore[p * SEQL + idx];
        s[q] = a;
    }
    float mx = fmaxf(fmaxf(s[0], s[1]), fmaxf(s[2], s[3]));
    #pragma unroll
    for (int off = 32; off; off >>= 1) mx = fmaxf(mx, __shfl_xor(mx, off));
    if (!lane) red[wv] = mx;
    __syncthreads();
    if (t == 0) {
        float m = red[0];
        for (int i = 1; i < 16; i++) m = fmaxf(m, red[i]);
        bcast = m;
    }
    __syncthreads();
    const float bm = bcast;
    float e[4], sum = 0.f;
    #pragma unroll
    for (int q = 0; q < 4; q++) { e[q] = __expf(s[q] - bm); sum += e[q]; }
    #pragma unroll
    for (int off = 32; off; off >>= 1) sum += __shfl_xor(sum, off);
    __syncthreads();
    if (!lane) red[wv] = sum;
    __syncthreads();
    if (t == 0) {
        float m = 0.f;
        for (int i = 0; i < 16; i++) m += red[i];
        bcast = m;
    }
    __syncthreads();
    const float inv = 1.f / bcast;
    #pragma unroll
    for (int q = 0; q < 4; q++) attnw[q * 1024 + t] = e[q] * inv;
}

// ---------------------------------------------------------------------------
// K_D: pweight[blk][h] = sum_{s in 8-chunk} a[s]*encbf[s,h]  (512 blocks)
__global__ __launch_bounds__(256)
void k_weighted_part(const unsigned short* __restrict__ encbf,
                     const float* __restrict__ attnw, float* __restrict__ pweight)
{
    const int blk = blockIdx.x;
    const int t = threadIdx.x;
    const int sbase = blk * 8;
    float acc[8];
    #pragma unroll
    for (int i = 0; i < 8; i++) acc[i] = 0.f;
    #pragma unroll
    for (int s = 0; s < 8; s++) {
        const float a = attnw[sbase + s];
        u16x8 v = *reinterpret_cast<const u16x8*>(encbf + (size_t)(sbase + s) * 2048 + t * 8);
        #pragma unroll
        for (int i = 0; i < 8; i++) acc[i] += a * bf2f(v[i]);
    }
    #pragma unroll
    for (int i = 0; i < 8; i++)
        pweight[(size_t)blk * 2048 + t * 8 + i] = acc[i];
}

// K_E: weighted[h] = sum over 512 pweight rows (64 blocks, 8 threads/h)
__global__ __launch_bounds__(256)
void k_weighted_reduce(const float* __restrict__ pweight, float* __restrict__ weighted)
{
    const int t = threadIdx.x;
    const int h = blockIdx.x * 32 + (t >> 3);
    const int slot = t & 7;
    float acc = 0.f;
    #pragma unroll 8
    for (int p = slot; p < 512; p += 8) acc += pweight[(size_t)p * 2048 + h];
    acc += __shfl_down(acc, 4);
    acc += __shfl_down(acc, 2);
    acc += __shfl_down(acc, 1);
    if (slot == 0) weighted[h] = acc;
}

// ---------------------------------------------------------------------------
// K_F: blocks 0..2047: finish gates with Wih[:,512:2560]@weighted + LSTM for t=blk.
//      blocks 2048..2175: out right-half: dout[n] = b_out[n] + Wout[n,2048:]@weighted
__global__ __launch_bounds__(256)
void k_gates_lstm_outR(const float* __restrict__ Wih, const float* __restrict__ weighted,
                       const float* __restrict__ gates, const float* __restrict__ c0,
                       const float* __restrict__ Wout, const float* __restrict__ b_out,
                       float* __restrict__ dout)
{
    __shared__ float sh[4];
    const int wv = threadIdx.x >> 6, lane = threadIdx.x & 63;
    if (blockIdx.x < 2048) {
        const int t = blockIdx.x;
        const int j = t + 2048 * wv;
        const float* Wr = Wih + (size_t)j * 2560 + 512;
        float s = 0.f;
        #pragma unroll
        for (int i = 0; i < 8; i++) {
            int c = i * 256 + lane * 4;
            float4 wvv = *reinterpret_cast<const float4*>(Wr + c);
            float4 hv = *reinterpret_cast<const float4*>(weighted + c);
            s += dot4(wvv, hv);
        }
        s = wave_sum(s);
        if (lane == 0) sh[wv] = s + gates[j];
        __syncthreads();
        if (threadIdx.x == 0) {
            const float gi = sh[0], gf = sh[1], gg = sh[2], go = sh[3];
            const float si = 1.f / (1.f + __expf(-gi));
            const float sf = 1.f / (1.f + __expf(-gf));
            const float so = 1.f / (1.f + __expf(-go));
            const float c = sf * c0[t] + si * tanhf(gg);
            const float h = so * tanhf(c);
            dout[512 + t]  = h;
            dout[2560 + t] = c;
        }
    } else {
        const int n = (blockIdx.x - 2048) * 4 + wv;   // 0..511
        const float* Wr = Wout + (size_t)n * 4096 + 2048;
        float s = 0.f;
        #pragma unroll
        for (int i = 0; i < 8; i++) {
            int c = i * 256 + lane * 4;
            float4 wvv = *reinterpret_cast<const float4*>(Wr + c);
            float4 hv = *reinterpret_cast<const float4*>(weighted + c);
            s += dot4(wvv, hv);
        }
        s = wave_sum(s);
        if (lane == 0) dout[n] = s + b_out[n];
    }
}

// ---------------------------------------------------------------------------
// K_G: dout[n] += Wout[n,0:2048] @ h_n
__global__ __launch_bounds__(256)
void k_out_left(const float* __restrict__ Wout, const float* __restrict__ hn,
                float* __restrict__ dout)
{
    const int n = (blockIdx.x * 256 + threadIdx.x) >> 6;   // 0..511
    const int lane = threadIdx.x & 63;
    const float* Wr = Wout + (size_t)n * 4096;
    float s = 0.f;
    #pragma unroll
    for (int i = 0; i < 8; i++) {
        int c = i * 256 + lane * 4;
        float4 wv = *reinterpret_cast<const float4*>(Wr + c);
        float4 hv = *reinterpret_cast<const float4*>(hn + c);
        s += dot4(wv, hv);
    }
    s = wave_sum(s);
    if (lane == 0) dout[n] += s;
}

// ---------------------------------------------------------------------------
extern "C" void kernel_launch(void* const* d_in, const int* in_sizes, int n_in,
                              void* d_out, int out_size, void* d_ws, size_t ws_size,
                              hipStream_t stream)
{
    const float* x        = (const float*)d_in[0];
    const float* ih       = (const float*)d_in[1];
    const float* ic       = (const float*)d_in[2];
    const float* enc      = (const float*)d_in[3];   // [4096,2048]
    const float* Wattn    = (const float*)d_in[4];   // [2048,4096]
    const float* b_attn   = (const float*)d_in[5];
    const float* v_attn   = (const float*)d_in[6];
    const float* Wih      = (const float*)d_in[7];   // [8192,2560]
    const float* Whh      = (const float*)d_in[8];   // [8192,2048]
    const float* b_ih     = (const float*)d_in[9];
    const float* b_hh     = (const float*)d_in[10];
    const float* Wout     = (const float*)d_in[11];  // [512,4096]
    const float* b_out    = (const float*)d_in[12];
    float* dout = (float*)d_out;   // [out 512][h_n 2048][c_n 2048]

    // ws: encbf 16MB | wbf 8MB (reused as pweight after K_B) | f32 scratch
    unsigned short* encbf = (unsigned short*)d_ws;                 // 8,388,608 u16
    unsigned short* wbf   = encbf + (size_t)8388608;               // 4,194,304 u16
    float* pweight  = (float*)wbf;        // 512*2048 f32 overlay (wbf dead after K_B)
    float* wsf      = (float*)(wbf + (size_t)4194304);
    float* h_pre    = wsf;                 // 2048
    float* gates    = wsf + 2048;          // 8192
    float* pscore   = wsf + 10240;         // 16*4096
    float* attnw    = wsf + 75776;         // 4096
    float* weighted = wsf + 79872;         // 2048

    k_conv_hpre_gates<<<8704, 256, 0, stream>>>(enc, Wattn, b_attn, ih,
                                                Wih, Whh, b_ih, b_hh, x,
                                                encbf, wbf, h_pre, gates);
    k_energy2<<<512, 256, 0, stream>>>(encbf, wbf, h_pre, v_attn, pscore);
    k_softmax<<<1, 1024, 0, stream>>>(pscore, attnw);
    k_weighted_part<<<512, 256, 0, stream>>>(encbf, attnw, pweight);
    k_weighted_reduce<<<64, 256, 0, stream>>>(pweight, weighted);
    k_gates_lstm_outR<<<2176, 256, 0, stream>>>(Wih, weighted, gates, ic,
                                                Wout, b_out, dout);
    k_out_left<<<128, 256, 0, stream>>>(Wout, dout + 512, dout);
}